// Round 2
// baseline (137.412 us; speedup 1.0000x reference)
//
#include <hip/hip_runtime.h>

typedef unsigned short u16;
typedef unsigned int u32;
typedef short s16x8 __attribute__((ext_vector_type(8)));
typedef short s16x4 __attribute__((ext_vector_type(4)));
typedef float f32x4 __attribute__((ext_vector_type(4)));

// ---- workspace byte offsets (total 4,259,840 B) ----
// uT/vT: [b][h][k] bf16, 2 MLPs; W2t: [n][h] bf16, 2 MLPs; e_raw: f32 [b][i][j]
#define UT_D   0u
#define VT_D   524288u
#define UT_N   1048576u
#define VT_N   1572864u
#define W2T_D  2097152u
#define W2T_N  2129920u
#define ERAW   2162688u

__device__ __forceinline__ float bf2f(u16 v) { return __uint_as_float(((u32)v) << 16); }
__device__ __forceinline__ u16 f2bf(float x) {
  u32 u = __float_as_uint(x);
  return (u16)((u + 0x7FFFu + ((u >> 16) & 1u)) >> 16);   // RNE
}

// =====================================================================
// kernel 1: per-agent layer-1 projections, both MLPs (f32 accumulate).
// u'[b,k,h] = ai@W1_ai + zi_m@W1_zim + zi_lv@W1_zilv + b1   (i-side rows)
// v [b,k,h] = aj@W1_aj + zj_m@W1_zjm + zj_lv@W1_zjlv        (j-side rows)
// dir rows:  ai=0..63, aj=64..127, geom=128..132, zi_m=133.., zi_lv=165..,
//            zj_m=197.., zj_lv=229..   (aoff=0, v = u_row + 64)
// none rows: geom=0..4, ai=5..68, aj=69..132, z* same as dir (aoff=5)
// Stored TRANSPOSED [b][h][k] bf16 for coalesced B2t loads in k_main.
__global__ __launch_bounds__(128) void k_uv(
    const float* __restrict__ af, const float* __restrict__ zm, const float* __restrict__ zlv,
    const float* __restrict__ W1d, const float* __restrict__ b1d,
    const float* __restrict__ W1n, const float* __restrict__ b1n,
    u16* __restrict__ ws16) {
  const int a   = blockIdx.x;    // agent 0..2047  (b = a>>8, k = a&255)
  const int mlp = blockIdx.y;    // 0 = dir, 1 = none
  const int t   = threadIdx.x;   // h
  __shared__ float xs[128];
  if (t < 64)      xs[t] = af[a*64 + t];
  else if (t < 96) xs[t] = zm[a*32 + (t-64)];
  else             xs[t] = zlv[a*32 + (t-96)];
  __syncthreads();
  const float* W1 = mlp ? W1n : W1d;
  const float* b1 = mlp ? b1n : b1d;
  const int aoff = mlp ? 5 : 0;
  float accU = b1[t];
  float accV = 0.f;
  #pragma unroll 4
  for (int f = 0; f < 64; ++f) {
    const float x = xs[f];
    accU = fmaf(x, W1[(f + aoff)*128 + t], accU);
    accV = fmaf(x, W1[(f + aoff + 64)*128 + t], accV);
  }
  #pragma unroll 4
  for (int f = 64; f < 128; ++f) {
    const float x = xs[f];
    accU = fmaf(x, W1[(69 + f)*128 + t], accU);   // zi rows
    accV = fmaf(x, W1[(133 + f)*128 + t], accV);  // zj rows
  }
  const int b = a >> 8, k = a & 255;
  u16* uT = (u16*)((char*)ws16 + (mlp ? UT_N : UT_D));
  u16* vT = (u16*)((char*)ws16 + (mlp ? VT_N : VT_D));
  uT[(b*128 + t)*256 + k] = f2bf(accU);
  vT[(b*128 + t)*256 + k] = f2bf(accV);
}

// kernel 1b: W2^T [n][h] bf16 into ws for both MLPs (A-operand of pass 2).
__global__ __launch_bounds__(256) void k_w2t(
    const float* __restrict__ W2d, const float* __restrict__ W2n, u16* __restrict__ ws16) {
  const int mlp = blockIdx.x, t = threadIdx.x;
  const float* W2 = mlp ? W2n : W2d;
  u16* W2t = (u16*)((char*)ws16 + (mlp ? W2T_N : W2T_D));
  for (int idx = t; idx < 16384; idx += 256) {
    const int h = idx >> 7, n = idx & 127;
    W2t[n*128 + h] = f2bf(W2[idx]);
  }
}

// =====================================================================
// kernel 2: main. One block per (b, 16 i's, 8 j's) = 128 pairs, 256 threads.
// Pass1: pre1^T[h,p] = B2t[h,k(32)] x A2t[k,p]  (one-hot folds u'_i+v_j; geom@Wg)
// Pass2: h2^T[n,p]   = W2t[n,h]     x h1[h,p]   (h1 in XOR-swizzled LDS)
// Pass3: e[p] = sum_n relu(h2+b2)*W3 + b3  (in-lane + shfl + cross-wave LDS)
__global__ __launch_bounds__(256, 2) void k_main(
    const float* __restrict__ af, const float* __restrict__ mask,
    const float* __restrict__ W1d, const float* __restrict__ b2d, const float* __restrict__ W3d, const float* __restrict__ b3d,
    const float* __restrict__ W1n, const float* __restrict__ b2n, const float* __restrict__ W3n, const float* __restrict__ b3n,
    const u16* __restrict__ ws16, float* __restrict__ e_raw, float* __restrict__ out) {
  const int t  = threadIdx.x;
  const int j0 = blockIdx.x * 8, i0 = blockIdx.y * 16, b = blockIdx.z;

  __shared__ u16 A2t[128][40];     // [pair][k0..31 + pad]  (B-operand pass1)
  __shared__ u16 B2t[128][40];     // [h][k0..31 + pad]     (A-operand pass1)
  __shared__ u16 h1s[128*128];     // [p][h] bf16, XOR-swizzled
  __shared__ float e_wave[4][128];
  __shared__ float ai4[16][4], aj4[8][4];
  __shared__ float maskI[16], maskJ[8];
  __shared__ float b2f[128], w3f[128];

  // ---- phase 0: stage geom components (0,1,3,4) + masks ----
  if (t < 64) {
    const int i = t >> 2, c = t & 3, cm = c + (c >> 1);      // 0,1,3,4
    ai4[i][c] = af[(b*256 + i0 + i)*64 + cm];
  } else if (t < 96) {
    const int j = (t-64) >> 2, c = t & 3, cm = c + (c >> 1);
    aj4[j][c] = af[(b*256 + j0 + j)*64 + cm];
  } else if (t < 112) {
    maskI[t-96] = mask[b*256 + i0 + (t-96)];
  } else if (t < 120) {
    maskJ[t-112] = mask[b*256 + j0 + (t-112)];
  }
  __syncthreads();

  // ---- A2t build (shared by both MLPs): [onehot_i(16)|onehot_j(8)|geom(5)|0] ----
  if (t >= 128) {
    const int p = t - 128, il = p >> 3, jl = p & 7;
    const float rp0 = aj4[jl][0]-ai4[il][0], rp1 = aj4[jl][1]-ai4[il][1];
    const float rv0 = aj4[jl][2]-ai4[il][2], rv1 = aj4[jl][3]-ai4[il][3];
    const float dist = sqrtf(rp0*rp0 + rp1*rp1);
    u16 row[32];
    #pragma unroll
    for (int k = 0; k < 32; ++k) {
      u16 v = 0;
      if (k < 16)       v = (k == il) ? (u16)0x3F80 : (u16)0;
      else if (k < 24)  v = ((k-16) == jl) ? (u16)0x3F80 : (u16)0;
      else if (k == 24) v = f2bf(rp0);
      else if (k == 25) v = f2bf(rp1);
      else if (k == 26) v = f2bf(rv0);
      else if (k == 27) v = f2bf(rv1);
      else if (k == 28) v = f2bf(dist);
      row[k] = v;
    }
    #pragma unroll
    for (int q = 0; q < 4; ++q) *(s16x8*)&A2t[p][q*8] = *(s16x8*)&row[q*8];
  }

  const int wv = t >> 6, l = t & 63, x = l & 15, g = l >> 4;

  #pragma unroll 1
  for (int ml = 0; ml < 2; ++ml) {
    const u16 *uT, *vT, *W2t; const float *W1, *b2, *W3, *b3; int grow;
    if (ml == 0) { uT = (const u16*)((const char*)ws16 + UT_D); vT = (const u16*)((const char*)ws16 + VT_D);
                   W1 = W1d; W2t = (const u16*)((const char*)ws16 + W2T_D); b2 = b2d; W3 = W3d; b3 = b3d; grow = 128; }
    else         { uT = (const u16*)((const char*)ws16 + UT_N); vT = (const u16*)((const char*)ws16 + VT_N);
                   W1 = W1n; W2t = (const u16*)((const char*)ws16 + W2T_N); b2 = b2n; W3 = W3n; b3 = b3n; grow = 0; }

    // ---- build B2t rows (t<128) ; stage b2/W3 f32 (t>=128) ----
    if (t < 128) {
      const int h = t;
      const u16* up = uT + (b*128 + h)*256 + i0;
      *(s16x8*)&B2t[h][0]  = *(const s16x8*)(up);
      *(s16x8*)&B2t[h][8]  = *(const s16x8*)(up + 8);
      const u16* vp = vT + (b*128 + h)*256 + j0;
      *(s16x8*)&B2t[h][16] = *(const s16x8*)(vp);
      u16 gw[8];
      #pragma unroll
      for (int gg = 0; gg < 5; ++gg) gw[gg] = f2bf(W1[(grow+gg)*128 + h]);
      gw[5] = gw[6] = gw[7] = 0;
      *(s16x8*)&B2t[h][24] = *(s16x8*)&gw[0];
    } else {
      const int h = t - 128;
      b2f[h] = b2[h];
      w3f[h] = W3[h];
    }
    __syncthreads();

    // ---- pass 1: pre1^T = B2t x A2t (K=32, one MFMA step) ----
    f32x4 acc1[2][8];
    {
      s16x8 Af0 = *(const s16x8*)&B2t[32*wv + x][8*g];
      s16x8 Af1 = *(const s16x8*)&B2t[32*wv + 16 + x][8*g];
      const f32x4 z = {0.f, 0.f, 0.f, 0.f};
      #pragma unroll
      for (int n = 0; n < 8; ++n) {
        s16x8 Bf = *(const s16x8*)&A2t[16*n + x][8*g];
        acc1[0][n] = __builtin_amdgcn_mfma_f32_16x16x32_bf16(Af0, Bf, z, 0, 0, 0);
        acc1[1][n] = __builtin_amdgcn_mfma_f32_16x16x32_bf16(Af1, Bf, z, 0, 0, 0);
      }
    }
    // relu -> bf16 -> h1s[p][h] (4 h-contiguous per store, XOR swizzle both sides)
    #pragma unroll
    for (int mm = 0; mm < 2; ++mm) {
      const int hb = 32*wv + 16*mm + 4*g;
      #pragma unroll
      for (int n = 0; n < 8; ++n) {
        const int p = 16*n + x;
        f32x4 v = acc1[mm][n];
        s16x4 pk;
        pk[0] = (short)f2bf(fmaxf(v[0], 0.f));
        pk[1] = (short)f2bf(fmaxf(v[1], 0.f));
        pk[2] = (short)f2bf(fmaxf(v[2], 0.f));
        pk[3] = (short)f2bf(fmaxf(v[3], 0.f));
        const int idx = (p*128 + hb) ^ ((p & 7) << 3);
        *(s16x4*)&h1s[idx] = pk;
      }
    }
    __syncthreads();

    // ---- pass 2: h2^T = W2t x h1 (K=128) ; W2^T frags straight from L2 ----
    f32x4 acc2[2][8];
    #pragma unroll
    for (int mm = 0; mm < 2; ++mm)
      #pragma unroll
      for (int n = 0; n < 8; ++n) acc2[mm][n] = (f32x4){0.f, 0.f, 0.f, 0.f};
    s16x8 w2fr[2][4];
    #pragma unroll
    for (int mm = 0; mm < 2; ++mm)
      #pragma unroll
      for (int kk = 0; kk < 4; ++kk)
        w2fr[mm][kk] = *(const s16x8*)(W2t + (32*wv + 16*mm + x)*128 + 32*kk + 8*g);
    #pragma unroll
    for (int kk = 0; kk < 4; ++kk) {
      #pragma unroll
      for (int n = 0; n < 8; ++n) {
        const int p = 16*n + x;
        const int idx = (p*128 + 32*kk + 8*g) ^ ((p & 7) << 3);
        s16x8 Bf = *(const s16x8*)&h1s[idx];
        acc2[0][n] = __builtin_amdgcn_mfma_f32_16x16x32_bf16(w2fr[0][kk], Bf, acc2[0][n], 0, 0, 0);
        acc2[1][n] = __builtin_amdgcn_mfma_f32_16x16x32_bf16(w2fr[1][kk], Bf, acc2[1][n], 0, 0, 0);
      }
    }

    // ---- pass 3: e[p] = sum_n relu(h2+b2)*W3 ----
    f32x4 b2v0 = *(const f32x4*)&b2f[32*wv + 4*g];
    f32x4 b2v1 = *(const f32x4*)&b2f[32*wv + 16 + 4*g];
    f32x4 w3v0 = *(const f32x4*)&w3f[32*wv + 4*g];
    f32x4 w3v1 = *(const f32x4*)&w3f[32*wv + 16 + 4*g];
    #pragma unroll
    for (int n = 0; n < 8; ++n) {
      float ep = 0.f;
      #pragma unroll
      for (int r = 0; r < 4; ++r) {
        ep += fmaxf(acc2[0][n][r] + b2v0[r], 0.f) * w3v0[r];
        ep += fmaxf(acc2[1][n][r] + b2v1[r], 0.f) * w3v1[r];
      }
      ep += __shfl_xor(ep, 16);
      ep += __shfl_xor(ep, 32);
      if (l < 16) e_wave[wv][16*n + l] = ep;
    }
    __syncthreads();

    // ---- finalize ----
    if (t < 128) {
      const int p = t, il = p >> 3, jl = p & 7;
      const float e = e_wave[0][p] + e_wave[1][p] + e_wave[2][p] + e_wave[3][p] + b3[0];
      const int i = i0 + il, j = j0 + jl;
      const bool keep = (maskI[il] * maskJ[jl] > 0.5f) && (i != j);
      const int off = (b << 16) + (i << 8) + j;
      if (ml == 0) out[off] = keep ? e : 1000000.0f;
      else         e_raw[off] = e;
    }
    __syncthreads();
  }
}

// =====================================================================
// kernel 3: e_none symmetrize + mask (keep-mask is symmetric, so averaging
// raw values == reference's mask-then-average).
__global__ __launch_bounds__(256) void k_sym(
    const float* __restrict__ e_raw, const float* __restrict__ mask, float* __restrict__ out) {
  const int gid = blockIdx.x * 256 + threadIdx.x;   // 0..524287
  const int j = gid & 255, i = (gid >> 8) & 255, b = gid >> 16;
  const float mi = mask[b*256 + i], mj = mask[b*256 + j];
  float v = 1000000.0f;
  if ((mi * mj > 0.5f) && (i != j))
    v = 0.5f * (e_raw[gid] + e_raw[(b << 16) + (j << 8) + i]);
  out[524288 + gid] = v;
}

extern "C" void kernel_launch(void* const* d_in, const int* in_sizes, int n_in,
                              void* d_out, int out_size, void* d_ws, size_t ws_size,
                              hipStream_t stream) {
  const float* af   = (const float*)d_in[0];
  const float* zm   = (const float*)d_in[1];
  const float* zlv  = (const float*)d_in[2];
  const float* mask = (const float*)d_in[3];
  const float* W1d  = (const float*)d_in[4];
  const float* b1d  = (const float*)d_in[5];
  const float* W2d  = (const float*)d_in[6];
  const float* b2d  = (const float*)d_in[7];
  const float* W3d  = (const float*)d_in[8];
  const float* b3d  = (const float*)d_in[9];
  const float* W1n  = (const float*)d_in[10];
  const float* b1n  = (const float*)d_in[11];
  const float* W2n  = (const float*)d_in[12];
  const float* b2n  = (const float*)d_in[13];
  const float* W3n  = (const float*)d_in[14];
  const float* b3n  = (const float*)d_in[15];

  u16*   ws16  = (u16*)d_ws;
  float* e_raw = (float*)((char*)d_ws + ERAW);
  float* out   = (float*)d_out;

  k_uv <<<dim3(2048, 2), 128, 0, stream>>>(af, zm, zlv, W1d, b1d, W1n, b1n, ws16);
  k_w2t<<<dim3(2),       256, 0, stream>>>(W2d, W2n, ws16);
  k_main<<<dim3(32, 16, 8), 256, 0, stream>>>(af, mask, W1d, b2d, W3d, b3d,
                                              W1n, b2n, W3n, b3n, ws16, e_raw, out);
  k_sym<<<dim3(2048), 256, 0, stream>>>(e_raw, mask, out);
}

// Round 3
// 117.315 us; speedup vs baseline: 1.1713x; 1.1713x over previous
//
#include <hip/hip_runtime.h>

typedef unsigned short u16;
typedef unsigned int u32;
typedef short s16x8 __attribute__((ext_vector_type(8)));
typedef short s16x4 __attribute__((ext_vector_type(4)));
typedef float f32x4 __attribute__((ext_vector_type(4)));
typedef u32 u32x2 __attribute__((ext_vector_type(2)));

// ---- workspace byte offsets ----
// uT/vT: [b][h][k] bf16, 2 MLPs; W2t: [n][h] bf16, 2 MLPs; e_raw: f32 [b][i][j]
#define UT_D   0u
#define VT_D   524288u
#define UT_N   1048576u
#define VT_N   1572864u
#define W2T_D  2097152u
#define W2T_N  2129920u
#define ERAW   2162688u

__device__ __forceinline__ float bf2f(u16 v) { return __uint_as_float(((u32)v) << 16); }
__device__ __forceinline__ u16 f2bf(float x) {
  u32 u = __float_as_uint(x);
  return (u16)((u + 0x7FFFu + ((u >> 16) & 1u)) >> 16);   // RNE
}
__device__ __forceinline__ u32 cvt_pk_bf16(float lo, float hi) {
  u32 r;
  asm("v_cvt_pk_bf16_f32 %0, %1, %2" : "=v"(r) : "v"(lo), "v"(hi));
  return r;
}

// =====================================================================
// kernel 1: per-agent layer-1 projections, both MLPs. 8 agents per block,
// x staged in LDS (uniform-address broadcast reads) so W1 is read once per
// block instead of once per agent: W1 L2 traffic 537MB -> 67MB.
__global__ __launch_bounds__(256) void k_uv(
    const float* __restrict__ af, const float* __restrict__ zm, const float* __restrict__ zlv,
    const float* __restrict__ W1d, const float* __restrict__ b1d,
    const float* __restrict__ W1n, const float* __restrict__ b1n,
    u16* __restrict__ ws16) {
  const int a0  = blockIdx.x * 8;    // agents a0..a0+7 (same b: 8 | 256)
  const int mlp = blockIdx.y;
  const int t   = threadIdx.x;       // h = t&127, half = t>>7 (0=U,1=V)
  __shared__ float xs[8][128];
  for (int idx = t; idx < 1024; idx += 256) {
    const int a = idx >> 7, f = idx & 127, ga = a0 + a;
    float v;
    if (f < 64)      v = af[ga*64 + f];
    else if (f < 96) v = zm[ga*32 + (f-64)];
    else             v = zlv[ga*32 + (f-96)];
    xs[a][f] = v;
  }
  __syncthreads();
  const int h = t & 127, half = t >> 7;
  const float* W1 = mlp ? W1n : W1d;
  const int aoff = (mlp ? 5 : 0) + 64*half;   // agent-feature rows
  const int zoff = 69 + 64*half;              // z rows (row = zoff + f)
  float acc[8];
  #pragma unroll
  for (int a = 0; a < 8; ++a) acc[a] = 0.f;
  #pragma unroll 2
  for (int f = 0; f < 64; f += 4) {
    const float w0 = W1[(aoff+f  )*128 + h];
    const float w1 = W1[(aoff+f+1)*128 + h];
    const float w2 = W1[(aoff+f+2)*128 + h];
    const float w3 = W1[(aoff+f+3)*128 + h];
    #pragma unroll
    for (int a = 0; a < 8; ++a) {
      const f32x4 xv = *(const f32x4*)&xs[a][f];
      acc[a] = fmaf(xv[3], w3, fmaf(xv[2], w2, fmaf(xv[1], w1, fmaf(xv[0], w0, acc[a]))));
    }
  }
  #pragma unroll 2
  for (int f = 64; f < 128; f += 4) {
    const float w0 = W1[(zoff+f  )*128 + h];
    const float w1 = W1[(zoff+f+1)*128 + h];
    const float w2 = W1[(zoff+f+2)*128 + h];
    const float w3 = W1[(zoff+f+3)*128 + h];
    #pragma unroll
    for (int a = 0; a < 8; ++a) {
      const f32x4 xv = *(const f32x4*)&xs[a][f];
      acc[a] = fmaf(xv[3], w3, fmaf(xv[2], w2, fmaf(xv[1], w1, fmaf(xv[0], w0, acc[a]))));
    }
  }
  const float bb = half ? 0.f : (mlp ? b1n[h] : b1d[h]);
  u16 pk[8];
  #pragma unroll
  for (int a = 0; a < 8; ++a) pk[a] = f2bf(acc[a] + bb);
  const int b = a0 >> 8;
  u16* dT = (u16*)((char*)ws16 + (mlp ? (half ? VT_N : UT_N) : (half ? VT_D : UT_D)));
  *(s16x8*)(dT + (b*128 + h)*256 + (a0 & 255)) = *(s16x8*)pk;   // 16B store
}

// kernel 1b: W2^T [n][h] bf16 into ws for both MLPs (A-operand of pass 2).
__global__ __launch_bounds__(256) void k_w2t(
    const float* __restrict__ W2d, const float* __restrict__ W2n, u16* __restrict__ ws16) {
  const int mlp = blockIdx.x, ch = blockIdx.y, t = threadIdx.x;
  const float* W2 = mlp ? W2n : W2d;
  u16* W2t = (u16*)((char*)ws16 + (mlp ? W2T_N : W2T_D));
  int idx = ch*2048 + t;
  #pragma unroll
  for (int r = 0; r < 8; ++r, idx += 256) {
    const int h = idx >> 7, n = idx & 127;
    W2t[n*128 + h] = f2bf(W2[idx]);
  }
}

// =====================================================================
// kernel 2: main. One block per (b, 16 i's, 8 j's) = 128 pairs, 256 threads.
// Pass1: pre1^T[h,p] = [u'_i | v_j | Wg] x A2t[k(32),p]  (A-frags straight
//        from global uT/vT/W1 -- zero LDS reuse so no staging; one-hot cols
//        of A2t fold u'_i + v_j into the MFMA)
// Pass2: h2^T[n,p]   = W2t[n,h] x h1[h,p]   (h1 in XOR-swizzled LDS)
// Pass3: e[p] = sum_n relu(h2+b2)*W3 + b3
__global__ __launch_bounds__(256, 3) void k_main(
    const float* __restrict__ af, const float* __restrict__ mask,
    const float* __restrict__ W1d, const float* __restrict__ b2d, const float* __restrict__ W3d, const float* __restrict__ b3d,
    const float* __restrict__ W1n, const float* __restrict__ b2n, const float* __restrict__ W3n, const float* __restrict__ b3n,
    const u16* __restrict__ ws16, float* __restrict__ e_raw, float* __restrict__ out) {
  const int t  = threadIdx.x;
  const int j0 = blockIdx.x * 8, i0 = blockIdx.y * 16, b = blockIdx.z;

  __shared__ u16 A2t[128][40];     // [pair][k + pad]  (B-operand pass1, 4x reuse)
  __shared__ u16 h1s[16384];       // [p][h] bf16, XOR-swizzled
  __shared__ float e_wave[4][128];
  __shared__ float ai4[16][4], aj4[8][4];
  __shared__ float maskI[16], maskJ[8];
  __shared__ float b2f2[2][128], w3f2[2][128];

  // ---- phase 0: stage geom components (0,1,3,4) + masks + b2/W3 ----
  if (t < 64) {
    const int i = t >> 2, c = t & 3, cm = c + (c >> 1);      // 0,1,3,4
    ai4[i][c] = af[(b*256 + i0 + i)*64 + cm];
  } else if (t < 96) {
    const int j = (t-64) >> 2, c = t & 3, cm = c + (c >> 1);
    aj4[j][c] = af[(b*256 + j0 + j)*64 + cm];
  } else if (t < 112) {
    maskI[t-96] = mask[b*256 + i0 + (t-96)];
  } else if (t < 120) {
    maskJ[t-112] = mask[b*256 + j0 + (t-112)];
  }
  if (t < 128) { b2f2[0][t] = b2d[t];     w3f2[0][t] = W3d[t]; }
  else         { b2f2[1][t-128] = b2n[t-128]; w3f2[1][t-128] = W3n[t-128]; }

  const int wv = t >> 6, l = t & 63, x = l & 15, g = l >> 4;

  // ---- preload pass-1 A-fragments for BOTH MLPs from global (L2-resident).
  // A-frag row h = 32wv + 16mm + x; k = 8g..8g+7:
  //   k in [0,16): u'_i columns i0+k     (g=0,1 -> 16B load from uT)
  //   k in [16,24): v_j columns j0+(k-16) (g=2  -> 16B load from vT)
  //   k in [24,32): geom weights W1[grow+gg][h], gg<5, rest 0 (g=3)
  s16x8 Af[2][2];
  #pragma unroll
  for (int ml = 0; ml < 2; ++ml) {
    const u16* uT = (const u16*)((const char*)ws16 + (ml ? UT_N : UT_D));
    const u16* vT = (const u16*)((const char*)ws16 + (ml ? VT_N : VT_D));
    const float* W1 = ml ? W1n : W1d;
    const int grow = ml ? 0 : 128;
    #pragma unroll
    for (int mm = 0; mm < 2; ++mm) {
      const int h = 32*wv + 16*mm + x;
      if (g < 2) {
        Af[ml][mm] = *(const s16x8*)(uT + (b*128 + h)*256 + i0 + 8*g);
      } else if (g == 2) {
        Af[ml][mm] = *(const s16x8*)(vT + (b*128 + h)*256 + j0);
      } else {
        u16 gw[8];
        #pragma unroll
        for (int gg = 0; gg < 5; ++gg) gw[gg] = f2bf(W1[(grow+gg)*128 + h]);
        gw[5] = gw[6] = gw[7] = 0;
        Af[ml][mm] = *(s16x8*)gw;
      }
    }
  }
  __syncthreads();   // B1: geom/masks staged

  // ---- A2t build (shared by both MLPs): [onehot_i(16)|onehot_j(8)|geom(5)|0]
  if (t >= 128) {
    const int p = t - 128, il = p >> 3, jl = p & 7;
    const float rp0 = aj4[jl][0]-ai4[il][0], rp1 = aj4[jl][1]-ai4[il][1];
    const float rv0 = aj4[jl][2]-ai4[il][2], rv1 = aj4[jl][3]-ai4[il][3];
    const float dist = sqrtf(rp0*rp0 + rp1*rp1);
    u16 row[32];
    #pragma unroll
    for (int k = 0; k < 32; ++k) {
      u16 v = 0;
      if (k < 16)       v = (k == il) ? (u16)0x3F80 : (u16)0;
      else if (k < 24)  v = ((k-16) == jl) ? (u16)0x3F80 : (u16)0;
      else if (k == 24) v = f2bf(rp0);
      else if (k == 25) v = f2bf(rp1);
      else if (k == 26) v = f2bf(rv0);
      else if (k == 27) v = f2bf(rv1);
      else if (k == 28) v = f2bf(dist);
      row[k] = v;
    }
    #pragma unroll
    for (int q = 0; q < 4; ++q) *(s16x8*)&A2t[t-128][q*8] = *(s16x8*)&row[q*8];
  }
  __syncthreads();   // B2: A2t ready

  #pragma unroll 1
  for (int ml = 0; ml < 2; ++ml) {
    const u16* W2t = (const u16*)((const char*)ws16 + (ml ? W2T_N : W2T_D));

    // ---- pass 2 A-operand (W2^T) loads issued early to hide L2 latency ----
    s16x8 w2fr[2][4];
    #pragma unroll
    for (int mm = 0; mm < 2; ++mm)
      #pragma unroll
      for (int kk = 0; kk < 4; ++kk)
        w2fr[mm][kk] = *(const s16x8*)(W2t + (32*wv + 16*mm + x)*128 + 32*kk + 8*g);

    // ---- pass 1: pre1^T = Af x A2t (K=32, one MFMA step) ----
    f32x4 acc1[2][8];
    {
      const f32x4 z = {0.f, 0.f, 0.f, 0.f};
      #pragma unroll
      for (int n = 0; n < 8; ++n) {
        s16x8 Bf = *(const s16x8*)&A2t[16*n + x][8*g];
        acc1[0][n] = __builtin_amdgcn_mfma_f32_16x16x32_bf16(Af[ml][0], Bf, z, 0, 0, 0);
        acc1[1][n] = __builtin_amdgcn_mfma_f32_16x16x32_bf16(Af[ml][1], Bf, z, 0, 0, 0);
      }
    }
    // relu -> bf16 (v_cvt_pk) -> h1s[p][h], XOR swizzle both sides
    #pragma unroll
    for (int mm = 0; mm < 2; ++mm) {
      const int hb = 32*wv + 16*mm + 4*g;
      #pragma unroll
      for (int n = 0; n < 8; ++n) {
        const int p = 16*n + x;
        const f32x4 v = acc1[mm][n];
        u32x2 pk;
        pk[0] = cvt_pk_bf16(fmaxf(v[0], 0.f), fmaxf(v[1], 0.f));
        pk[1] = cvt_pk_bf16(fmaxf(v[2], 0.f), fmaxf(v[3], 0.f));
        const int idx = (p*128 + hb) ^ ((x & 7) << 3);
        *(u32x2*)&h1s[idx] = pk;   // 8B store
      }
    }
    __syncthreads();   // B3: h1s ready

    // ---- pass 2: h2^T = W2t x h1 (K=128) ----
    f32x4 acc2[2][8];
    #pragma unroll
    for (int mm = 0; mm < 2; ++mm)
      #pragma unroll
      for (int n = 0; n < 8; ++n) acc2[mm][n] = (f32x4){0.f, 0.f, 0.f, 0.f};
    __builtin_amdgcn_s_setprio(1);
    #pragma unroll
    for (int kk = 0; kk < 4; ++kk) {
      #pragma unroll
      for (int n = 0; n < 8; ++n) {
        const int p = 16*n + x;
        const int idx = (p*128 + 32*kk + 8*g) ^ ((x & 7) << 3);
        s16x8 Bf = *(const s16x8*)&h1s[idx];
        acc2[0][n] = __builtin_amdgcn_mfma_f32_16x16x32_bf16(w2fr[0][kk], Bf, acc2[0][n], 0, 0, 0);
        acc2[1][n] = __builtin_amdgcn_mfma_f32_16x16x32_bf16(w2fr[1][kk], Bf, acc2[1][n], 0, 0, 0);
      }
    }
    __builtin_amdgcn_s_setprio(0);

    // ---- pass 3: e[p] = sum_n relu(h2+b2)*W3 ----
    const f32x4 b2v0 = *(const f32x4*)&b2f2[ml][32*wv + 4*g];
    const f32x4 b2v1 = *(const f32x4*)&b2f2[ml][32*wv + 16 + 4*g];
    const f32x4 w3v0 = *(const f32x4*)&w3f2[ml][32*wv + 4*g];
    const f32x4 w3v1 = *(const f32x4*)&w3f2[ml][32*wv + 16 + 4*g];
    float ep[8];
    #pragma unroll
    for (int n = 0; n < 8; ++n) {
      float e = 0.f;
      #pragma unroll
      for (int r = 0; r < 4; ++r) {
        e += fmaxf(acc2[0][n][r] + b2v0[r], 0.f) * w3v0[r];
        e += fmaxf(acc2[1][n][r] + b2v1[r], 0.f) * w3v1[r];
      }
      e += __shfl_xor(e, 16);
      e += __shfl_xor(e, 32);
      ep[n] = e;
    }
    __syncthreads();   // B4: prior finalize done (e_wave safe to overwrite)
    #pragma unroll
    for (int n = 0; n < 8; ++n)
      if (l < 16) e_wave[wv][16*n + l] = ep[n];
    __syncthreads();   // B5: e_wave ready

    // ---- finalize ----
    if (t < 128) {
      const int p = t, il = p >> 3, jl = p & 7;
      const float b3v = ml ? b3n[0] : b3d[0];
      const float e = e_wave[0][p] + e_wave[1][p] + e_wave[2][p] + e_wave[3][p] + b3v;
      const int i = i0 + il, j = j0 + jl;
      const bool keep = (maskI[il] * maskJ[jl] > 0.5f) && (i != j);
      const int off = (b << 16) + (i << 8) + j;
      if (ml == 0) out[off] = keep ? e : 1000000.0f;
      else         e_raw[off] = e;
    }
  }
}

// =====================================================================
// kernel 3: e_none symmetrize + mask, tile-pair version: both reads and all
// writes coalesced; each unordered tile pair handled once via LDS transpose.
__global__ __launch_bounds__(256) void k_sym(
    const float* __restrict__ e_raw, const float* __restrict__ mask, float* __restrict__ out) {
  const int tp = blockIdx.x, b = blockIdx.y;
  int ti, tj;
  if (tp < 4)      { ti = 0; tj = tp; }
  else if (tp < 7) { ti = 1; tj = tp - 3; }
  else if (tp < 9) { ti = 2; tj = tp - 5; }
  else             { ti = 3; tj = 3; }
  __shared__ float E1[64][65], E2[64][65];
  __shared__ float mI[64], mJ[64];
  const int t = threadIdx.x;
  const int i0 = ti*64, j0 = tj*64, base = b << 16;
  for (int idx = t; idx < 4096; idx += 256) {
    const int r = idx >> 6, c = idx & 63;
    E1[r][c] = e_raw[base + (i0 + r)*256 + j0 + c];
    E2[r][c] = e_raw[base + (j0 + r)*256 + i0 + c];
  }
  if (t < 64)       mI[t] = mask[b*256 + i0 + t];
  else if (t < 128) mJ[t-64] = mask[b*256 + j0 + (t-64)];
  __syncthreads();
  for (int idx = t; idx < 4096; idx += 256) {
    const int r = idx >> 6, c = idx & 63;
    const int i = i0 + r, j = j0 + c;
    float v = 1000000.0f;
    if ((mI[r]*mJ[c] > 0.5f) && (i != j)) v = 0.5f*(E1[r][c] + E2[c][r]);
    out[524288 + base + i*256 + j] = v;
  }
  if (ti != tj) {
    for (int idx = t; idx < 4096; idx += 256) {
      const int r = idx >> 6, c = idx & 63;   // output row j0+r, col i0+c
      float v = 1000000.0f;
      if (mJ[r]*mI[c] > 0.5f) v = 0.5f*(E2[r][c] + E1[c][r]);
      out[524288 + base + (j0 + r)*256 + i0 + c] = v;
    }
  }
}

extern "C" void kernel_launch(void* const* d_in, const int* in_sizes, int n_in,
                              void* d_out, int out_size, void* d_ws, size_t ws_size,
                              hipStream_t stream) {
  const float* af   = (const float*)d_in[0];
  const float* zm   = (const float*)d_in[1];
  const float* zlv  = (const float*)d_in[2];
  const float* mask = (const float*)d_in[3];
  const float* W1d  = (const float*)d_in[4];
  const float* b1d  = (const float*)d_in[5];
  const float* W2d  = (const float*)d_in[6];
  const float* b2d  = (const float*)d_in[7];
  const float* W3d  = (const float*)d_in[8];
  const float* b3d  = (const float*)d_in[9];
  const float* W1n  = (const float*)d_in[10];
  const float* b1n  = (const float*)d_in[11];
  const float* W2n  = (const float*)d_in[12];
  const float* b2n  = (const float*)d_in[13];
  const float* W3n  = (const float*)d_in[14];
  const float* b3n  = (const float*)d_in[15];

  u16*   ws16  = (u16*)d_ws;
  float* e_raw = (float*)((char*)d_ws + ERAW);
  float* out   = (float*)d_out;

  k_uv <<<dim3(256, 2), 256, 0, stream>>>(af, zm, zlv, W1d, b1d, W1n, b1n, ws16);
  k_w2t<<<dim3(2, 8),   256, 0, stream>>>(W2d, W2n, ws16);
  k_main<<<dim3(32, 16, 8), 256, 0, stream>>>(af, mask, W1d, b2d, W3d, b3d,
                                              W1n, b2n, W3n, b3n, ws16, e_raw, out);
  k_sym<<<dim3(10, 8), 256, 0, stream>>>(e_raw, mask, out);
}

// Round 4
// 80.216 us; speedup vs baseline: 1.7130x; 1.4625x over previous
//
#include <hip/hip_runtime.h>

typedef unsigned short u16;
typedef unsigned int u32;
typedef short s16x8 __attribute__((ext_vector_type(8)));
typedef float f32x4 __attribute__((ext_vector_type(4)));
typedef u32 u32x4 __attribute__((ext_vector_type(4)));

// ---- workspace byte offsets ----
// uT/vT: [b][h][k] bf16 (u includes b1); W2s: sigma-permuted W2^T bf16; e_raw f32
#define UT_D   0u
#define VT_D   524288u
#define UT_N   1048576u
#define VT_N   1572864u
#define W2T_D  2097152u
#define W2T_N  2129920u
#define ERAW   2162688u

__device__ __forceinline__ u16 f2bf(float x) {
  u32 u = __float_as_uint(x);
  return (u16)((u + 0x7FFFu + ((u >> 16) & 1u)) >> 16);   // RNE
}
__device__ __forceinline__ u32 cvt_pk_bf16(float lo, float hi) {
  u32 r;
  asm("v_cvt_pk_bf16_f32 %0, %1, %2" : "=v"(r) : "v"(lo), "v"(hi));
  return r;
}
__device__ __forceinline__ s16x8 as_frag(u32x4 v) { return __builtin_bit_cast(s16x8, v); }

// =====================================================================
// kernel 1: per-agent layer-1 projections (unchanged from R3; h in natural order).
__global__ __launch_bounds__(256) void k_uv(
    const float* __restrict__ af, const float* __restrict__ zm, const float* __restrict__ zlv,
    const float* __restrict__ W1d, const float* __restrict__ b1d,
    const float* __restrict__ W1n, const float* __restrict__ b1n,
    u16* __restrict__ ws16) {
  const int a0  = blockIdx.x * 8;
  const int mlp = blockIdx.y;
  const int t   = threadIdx.x;
  __shared__ float xs[8][128];
  for (int idx = t; idx < 1024; idx += 256) {
    const int a = idx >> 7, f = idx & 127, ga = a0 + a;
    float v;
    if (f < 64)      v = af[ga*64 + f];
    else if (f < 96) v = zm[ga*32 + (f-64)];
    else             v = zlv[ga*32 + (f-96)];
    xs[a][f] = v;
  }
  __syncthreads();
  const int h = t & 127, half = t >> 7;
  const float* W1 = mlp ? W1n : W1d;
  const int aoff = (mlp ? 5 : 0) + 64*half;
  const int zoff = 69 + 64*half;
  float acc[8];
  #pragma unroll
  for (int a = 0; a < 8; ++a) acc[a] = 0.f;
  #pragma unroll 2
  for (int f = 0; f < 64; f += 4) {
    const float w0 = W1[(aoff+f  )*128 + h];
    const float w1 = W1[(aoff+f+1)*128 + h];
    const float w2 = W1[(aoff+f+2)*128 + h];
    const float w3 = W1[(aoff+f+3)*128 + h];
    #pragma unroll
    for (int a = 0; a < 8; ++a) {
      const f32x4 xv = *(const f32x4*)&xs[a][f];
      acc[a] = fmaf(xv[3], w3, fmaf(xv[2], w2, fmaf(xv[1], w1, fmaf(xv[0], w0, acc[a]))));
    }
  }
  #pragma unroll 2
  for (int f = 64; f < 128; f += 4) {
    const float w0 = W1[(zoff+f  )*128 + h];
    const float w1 = W1[(zoff+f+1)*128 + h];
    const float w2 = W1[(zoff+f+2)*128 + h];
    const float w3 = W1[(zoff+f+3)*128 + h];
    #pragma unroll
    for (int a = 0; a < 8; ++a) {
      const f32x4 xv = *(const f32x4*)&xs[a][f];
      acc[a] = fmaf(xv[3], w3, fmaf(xv[2], w2, fmaf(xv[1], w1, fmaf(xv[0], w0, acc[a]))));
    }
  }
  const float bb = half ? 0.f : (mlp ? b1n[h] : b1d[h]);
  u16 pk[8];
  #pragma unroll
  for (int a = 0; a < 8; ++a) pk[a] = f2bf(acc[a] + bb);
  const int b = a0 >> 8;
  u16* dT = (u16*)((char*)ws16 + (mlp ? (half ? VT_N : UT_N) : (half ? VT_D : UT_D)));
  *(s16x8*)(dT + (b*128 + h)*256 + (a0 & 255)) = *(s16x8*)pk;
}

// kernel 1b: sigma-permuted W2^T: W2s[nn*128 + k] = W2[h(k)][nn], bf16.
// k = 32kk+8g+4t+r  <->  h = 32kk+16t+4g+r  (in-lane pass1->pass2 chaining).
__global__ __launch_bounds__(256) void k_w2t(
    const float* __restrict__ W2d, const float* __restrict__ W2n, u16* __restrict__ ws16) {
  const int mlp = blockIdx.x, ch = blockIdx.y, t = threadIdx.x;
  const float* W2 = mlp ? W2n : W2d;
  u16* W2s = (u16*)((char*)ws16 + (mlp ? W2T_N : W2T_D));
  int idx = ch*2048 + t;
  #pragma unroll
  for (int rr = 0; rr < 8; ++rr, idx += 256) {
    const int nn = idx >> 7, k = idx & 127;
    const int h = 32*(k>>5) + 16*((k>>2)&1) + 4*((k>>3)&3) + (k&3);
    W2s[nn*128 + k] = f2bf(W2[h*128 + nn]);
  }
}

// =====================================================================
// kernel 2: main, barrier-free sigma-chained pipeline.
// Block: one mlp, 8 i's, 128 j's (4 steps x 4 waves x 8j). Wave owns 64 pairs.
// pass1: pre1[h,q] = [u'|v|0|Wg](A) x onehot/geom(B), K=32, acc->relu->bf16
//        packed IN-LANE into pass2 B-frags (sigma trick; no LDS, no barrier).
// pass2: h2[nn,q] = W2s(A, from swizzled LDS) x h1(B, registers), K=128.
// pass3: e[q] = sum relu(h2+b2)*W3 in-lane + 2 shfl; direct global write.
__global__ __launch_bounds__(256, 2) void k_main(
    const float* __restrict__ af, const float* __restrict__ mask,
    const float* __restrict__ W1d, const float* __restrict__ b2d, const float* __restrict__ W3d, const float* __restrict__ b3d,
    const float* __restrict__ W1n, const float* __restrict__ b2n, const float* __restrict__ W3n, const float* __restrict__ b3n,
    const u16* __restrict__ ws16, float* __restrict__ e_raw, float* __restrict__ out) {
  const int t   = threadIdx.x;
  const int i0  = blockIdx.x * 8;
  const int mlp = blockIdx.y & 1, jc = blockIdx.y >> 1;
  const int b   = blockIdx.z;

  __shared__ u16 w2s[16384];       // W2s, XOR-swizzled (byte ^= (row&7)<<4)
  __shared__ float b2w3f[2][128];
  __shared__ float maskF[256];

  const u16* W2s_g = (const u16*)((const char*)ws16 + (mlp ? W2T_N : W2T_D));
  {
    const int row = t >> 1, c0 = (t & 1) * 64;
    #pragma unroll
    for (int w = 0; w < 8; ++w) {
      s16x8 v = *(const s16x8*)(W2s_g + row*128 + c0 + w*8);
      const int idx = (row*128 + c0 + w*8) ^ ((row & 7) << 3);
      *(s16x8*)&w2s[idx] = v;
    }
  }
  if (t < 128) b2w3f[0][t] = (mlp ? b2n : b2d)[t];
  else         b2w3f[1][t-128] = (mlp ? W3n : W3d)[t-128];
  maskF[t] = mask[b*256 + t];
  const float b3v = (mlp ? b3n : b3d)[0];

  const int wv = t >> 6, l = t & 63, x = l & 15, g = l >> 4;
  const int xh = x >> 3, xl = x & 7;

  const u16* uT = (const u16*)((const char*)ws16 + (mlp ? UT_N : UT_D));
  const u16* vT = (const u16*)((const char*)ws16 + (mlp ? VT_N : VT_D));
  const float* W1 = mlp ? W1n : W1d;
  const int grow = mlp ? 0 : 128;

  // ---- persistent pass-1 A-frags: g0 = u'_i octet (block-static),
  //      g1 = v_j octet (per step), g2 = 0, g3 = Wg octet (static) ----
  s16x8 Af[8];
  #pragma unroll
  for (int m = 0; m < 8; ++m) {
    u32x4 a = {0u, 0u, 0u, 0u};
    if (g == 0) {
      a = *(const u32x4*)(uT + (b*128 + 16*m + x)*256 + i0);
    } else if (g == 3) {
      const int h = 16*m + x;
      const float w0 = W1[(grow+0)*128 + h], w1 = W1[(grow+1)*128 + h];
      const float w2 = W1[(grow+2)*128 + h], w3 = W1[(grow+3)*128 + h];
      const float w4 = W1[(grow+4)*128 + h];
      a[0] = cvt_pk_bf16(w0, w1); a[1] = cvt_pk_bf16(w2, w3);
      a[2] = cvt_pk_bf16(w4, 0.f); a[3] = 0u;
    }
    Af[m] = __builtin_bit_cast(s16x8, a);
  }

  // ---- static one-hot B-frags (g0: i-onehot, g1: j-onehot); g3 geom per step ----
  u32x4 B1u[4];
  #pragma unroll
  for (int n = 0; n < 4; ++n) {
    u32x4 v = {0u, 0u, 0u, 0u};
    if (g == 0) {
      const int il = 2*n + xh;
      v[il >> 1] = (il & 1) ? 0x3F800000u : 0x3F80u;
    } else if (g == 1) {
      v[xl >> 1] = (xl & 1) ? 0x3F800000u : 0x3F80u;
    }
    B1u[n] = v;
  }

  // ---- i-side geom components (block-static): comps 0,1,3,4 of i = i0+2n+xh ----
  f32x4 aic[4];
  #pragma unroll
  for (int n = 0; n < 4; ++n) {
    const float* ap = af + (b*256 + i0 + 2*n + xh)*64;
    aic[n][0] = ap[0]; aic[n][1] = ap[1]; aic[n][2] = ap[3]; aic[n][3] = ap[4];
  }

  int j0w = jc*128 + wv*8;
  // prefetch step-0 v-octets + j-side geom comps
  if (g == 1) {
    #pragma unroll
    for (int m = 0; m < 8; ++m)
      Af[m] = *(const s16x8*)(vT + (b*128 + 16*m + x)*256 + j0w);
  }
  float aj0, aj1, aj2, aj3;
  {
    const float* ap = af + (b*256 + j0w + xl)*64;
    aj0 = ap[0]; aj1 = ap[1]; aj2 = ap[3]; aj3 = ap[4];
  }

  __syncthreads();   // the only barrier: LDS staging complete

  const f32x4 zero4 = {0.f, 0.f, 0.f, 0.f};
  #pragma unroll 1
  for (int s = 0; s < 4; ++s, j0w += 32) {
    // ---- geom -> B1u g3 octet (k24..28 = rp0,rp1,rv0,rv1,dist) ----
    if (g == 3) {
      #pragma unroll
      for (int n = 0; n < 4; ++n) {
        const float rp0 = aj0 - aic[n][0], rp1 = aj1 - aic[n][1];
        const float rv0 = aj2 - aic[n][2], rv1 = aj3 - aic[n][3];
        const float dist = sqrtf(rp0*rp0 + rp1*rp1);
        u32x4 v;
        v[0] = cvt_pk_bf16(rp0, rp1); v[1] = cvt_pk_bf16(rv0, rv1);
        v[2] = cvt_pk_bf16(dist, 0.f); v[3] = 0u;
        B1u[n] = v;
      }
    }

    // ---- pass 1 + in-lane relu/pack into pass-2 B-frags (sigma chain) ----
    u32x4 Bh1[4][4];   // [kk][n]
    #pragma unroll
    for (int m = 0; m < 8; ++m) {
      #pragma unroll
      for (int n = 0; n < 4; ++n) {
        f32x4 a = __builtin_amdgcn_mfma_f32_16x16x32_bf16(Af[m], as_frag(B1u[n]), zero4, 0, 0, 0);
        const u32 p0 = cvt_pk_bf16(fmaxf(a[0], 0.f), fmaxf(a[1], 0.f));
        const u32 p1 = cvt_pk_bf16(fmaxf(a[2], 0.f), fmaxf(a[3], 0.f));
        if ((m & 1) == 0) { Bh1[m>>1][n][0] = p0; Bh1[m>>1][n][1] = p1; }
        else              { Bh1[m>>1][n][2] = p0; Bh1[m>>1][n][3] = p1; }
      }
    }

    // ---- prefetch next step's v-octets + geom comps (lands under pass2) ----
    if (s < 3) {
      if (g == 1) {
        #pragma unroll
        for (int m = 0; m < 8; ++m)
          Af[m] = *(const s16x8*)(vT + (b*128 + 16*m + x)*256 + j0w + 32);
      }
      const float* ap = af + (b*256 + j0w + 32 + xl)*64;
      aj0 = ap[0]; aj1 = ap[1]; aj2 = ap[3]; aj3 = ap[4];
    }

    // ---- pass 2 (W2s from swizzled LDS) + pass 3 (in-lane reduce) ----
    float ep0 = 0.f, ep1 = 0.f, ep2 = 0.f, ep3 = 0.f;
    #pragma unroll
    for (int nq = 0; nq < 4; ++nq) {
      f32x4 acc2[2][4];
      #pragma unroll
      for (int mq = 0; mq < 2; ++mq)
        #pragma unroll
        for (int n = 0; n < 4; ++n) acc2[mq][n] = zero4;
      #pragma unroll
      for (int kk = 0; kk < 4; ++kk) {
        #pragma unroll
        for (int mq = 0; mq < 2; ++mq) {
          const int idx = ((16*(2*nq+mq) + x)*128 + 32*kk + 8*g) ^ ((x & 7) << 3);
          const s16x8 a2 = *(const s16x8*)&w2s[idx];
          #pragma unroll
          for (int n = 0; n < 4; ++n)
            acc2[mq][n] = __builtin_amdgcn_mfma_f32_16x16x32_bf16(a2, as_frag(Bh1[kk][n]), acc2[mq][n], 0, 0, 0);
        }
      }
      #pragma unroll
      for (int mq = 0; mq < 2; ++mq) {
        const int nn0 = 16*(2*nq+mq) + 4*g;
        const f32x4 b2v = *(const f32x4*)&b2w3f[0][nn0];
        const f32x4 w3v = *(const f32x4*)&b2w3f[1][nn0];
        #pragma unroll
        for (int r = 0; r < 4; ++r) {
          ep0 += fmaxf(acc2[mq][0][r] + b2v[r], 0.f) * w3v[r];
          ep1 += fmaxf(acc2[mq][1][r] + b2v[r], 0.f) * w3v[r];
          ep2 += fmaxf(acc2[mq][2][r] + b2v[r], 0.f) * w3v[r];
          ep3 += fmaxf(acc2[mq][3][r] + b2v[r], 0.f) * w3v[r];
        }
      }
    }
    ep0 += __shfl_xor(ep0, 16); ep0 += __shfl_xor(ep0, 32);
    ep1 += __shfl_xor(ep1, 16); ep1 += __shfl_xor(ep1, 32);
    ep2 += __shfl_xor(ep2, 16); ep2 += __shfl_xor(ep2, 32);
    ep3 += __shfl_xor(ep3, 16); ep3 += __shfl_xor(ep3, 32);

    // lane writes pair q = 16g + x  ->  (iloc = 2g+xh, jloc = xl)
    const float es = (g == 0) ? ep0 : (g == 1) ? ep1 : (g == 2) ? ep2 : ep3;
    const int gi = i0 + 2*g + xh, gj = j0w + xl;
    const float e = es + b3v;
    const int off = (b << 16) + (gi << 8) + gj;
    if (mlp == 0) {
      const bool keep = (maskF[gi] * maskF[gj] > 0.5f) && (gi != gj);
      out[off] = keep ? e : 1000000.0f;
    } else {
      e_raw[off] = e;
    }
  }
}

// =====================================================================
// kernel 3: e_none symmetrize + mask (tile-pair, coalesced).
__global__ __launch_bounds__(256) void k_sym(
    const float* __restrict__ e_raw, const float* __restrict__ mask, float* __restrict__ out) {
  const int tp = blockIdx.x, b = blockIdx.y;
  int ti, tj;
  if (tp < 4)      { ti = 0; tj = tp; }
  else if (tp < 7) { ti = 1; tj = tp - 3; }
  else if (tp < 9) { ti = 2; tj = tp - 5; }
  else             { ti = 3; tj = 3; }
  __shared__ float E1[64][65], E2[64][65];
  __shared__ float mI[64], mJ[64];
  const int t = threadIdx.x;
  const int i0 = ti*64, j0 = tj*64, base = b << 16;
  for (int idx = t; idx < 4096; idx += 256) {
    const int r = idx >> 6, c = idx & 63;
    E1[r][c] = e_raw[base + (i0 + r)*256 + j0 + c];
    E2[r][c] = e_raw[base + (j0 + r)*256 + i0 + c];
  }
  if (t < 64)       mI[t] = mask[b*256 + i0 + t];
  else if (t < 128) mJ[t-64] = mask[b*256 + j0 + (t-64)];
  __syncthreads();
  for (int idx = t; idx < 4096; idx += 256) {
    const int r = idx >> 6, c = idx & 63;
    const int i = i0 + r, j = j0 + c;
    float v = 1000000.0f;
    if ((mI[r]*mJ[c] > 0.5f) && (i != j)) v = 0.5f*(E1[r][c] + E2[c][r]);
    out[524288 + base + i*256 + j] = v;
  }
  if (ti != tj) {
    for (int idx = t; idx < 4096; idx += 256) {
      const int r = idx >> 6, c = idx & 63;
      float v = 1000000.0f;
      if (mJ[r]*mI[c] > 0.5f) v = 0.5f*(E2[r][c] + E1[c][r]);
      out[524288 + base + (j0 + r)*256 + i0 + c] = v;
    }
  }
}

extern "C" void kernel_launch(void* const* d_in, const int* in_sizes, int n_in,
                              void* d_out, int out_size, void* d_ws, size_t ws_size,
                              hipStream_t stream) {
  const float* af   = (const float*)d_in[0];
  const float* zm   = (const float*)d_in[1];
  const float* zlv  = (const float*)d_in[2];
  const float* mask = (const float*)d_in[3];
  const float* W1d  = (const float*)d_in[4];
  const float* b1d  = (const float*)d_in[5];
  const float* W2d  = (const float*)d_in[6];
  const float* b2d  = (const float*)d_in[7];
  const float* W3d  = (const float*)d_in[8];
  const float* b3d  = (const float*)d_in[9];
  const float* W1n  = (const float*)d_in[10];
  const float* b1n  = (const float*)d_in[11];
  const float* W2n  = (const float*)d_in[12];
  const float* b2n  = (const float*)d_in[13];
  const float* W3n  = (const float*)d_in[14];
  const float* b3n  = (const float*)d_in[15];

  u16*   ws16  = (u16*)d_ws;
  float* e_raw = (float*)((char*)d_ws + ERAW);
  float* out   = (float*)d_out;

  k_uv <<<dim3(256, 2), 256, 0, stream>>>(af, zm, zlv, W1d, b1d, W1n, b1n, ws16);
  k_w2t<<<dim3(2, 8),   256, 0, stream>>>(W2d, W2n, ws16);
  k_main<<<dim3(32, 4, 8), 256, 0, stream>>>(af, mask, W1d, b2d, W3d, b3d,
                                             W1n, b2n, W3n, b3n, ws16, e_raw, out);
  k_sym<<<dim3(10, 8), 256, 0, stream>>>(e_raw, mask, out);
}

// Round 5
// 77.982 us; speedup vs baseline: 1.7621x; 1.0287x over previous
//
#include <hip/hip_runtime.h>

typedef unsigned short u16;
typedef unsigned int u32;
typedef short s16x8 __attribute__((ext_vector_type(8)));
typedef float f32x4 __attribute__((ext_vector_type(4)));
typedef u32 u32x4 __attribute__((ext_vector_type(4)));

// ---- workspace byte offsets ----
// uT/vT: [b][h][k] bf16 (u includes b1); W2s: sigma-permuted W2^T bf16; e_raw f32
#define UT_D   0u
#define VT_D   524288u
#define UT_N   1048576u
#define VT_N   1572864u
#define W2T_D  2097152u
#define W2T_N  2129920u
#define ERAW   2162688u

__device__ __forceinline__ u16 f2bf(float x) {
  u32 u = __float_as_uint(x);
  return (u16)((u + 0x7FFFu + ((u >> 16) & 1u)) >> 16);   // RNE
}
__device__ __forceinline__ u32 cvt_pk_bf16(float lo, float hi) {
  u32 r;
  asm("v_cvt_pk_bf16_f32 %0, %1, %2" : "=v"(r) : "v"(lo), "v"(hi));
  return r;
}
__device__ __forceinline__ s16x8 as_frag(u32x4 v) { return __builtin_bit_cast(s16x8, v); }

// =====================================================================
// kernel 1 (merged): blocks x<256: per-agent layer-1 projections.
//                    block x==256: sigma-permuted W2^T staging.
__global__ __launch_bounds__(256) void k_uvw(
    const float* __restrict__ af, const float* __restrict__ zm, const float* __restrict__ zlv,
    const float* __restrict__ W1d, const float* __restrict__ b1d,
    const float* __restrict__ W1n, const float* __restrict__ b1n,
    const float* __restrict__ W2d, const float* __restrict__ W2n,
    u16* __restrict__ ws16) {
  const int mlp = blockIdx.y;
  const int t   = threadIdx.x;
  if (blockIdx.x == 256) {
    // W2s[nn*128 + k] = W2[h(k)][nn];  k=32kk+8g+4tt+r <-> h=32kk+16tt+4g+r
    const float* W2 = mlp ? W2n : W2d;
    u16* W2s = (u16*)((char*)ws16 + (mlp ? W2T_N : W2T_D));
    for (int idx = t; idx < 16384; idx += 256) {
      const int nn = idx >> 7, k = idx & 127;
      const int h = 32*(k>>5) + 16*((k>>2)&1) + 4*((k>>3)&3) + (k&3);
      W2s[nn*128 + k] = f2bf(W2[h*128 + nn]);
    }
    return;
  }
  const int a0 = blockIdx.x * 8;
  __shared__ float xs[8][128];
  for (int idx = t; idx < 1024; idx += 256) {
    const int a = idx >> 7, f = idx & 127, ga = a0 + a;
    float v;
    if (f < 64)      v = af[ga*64 + f];
    else if (f < 96) v = zm[ga*32 + (f-64)];
    else             v = zlv[ga*32 + (f-96)];
    xs[a][f] = v;
  }
  __syncthreads();
  const int h = t & 127, half = t >> 7;
  const float* W1 = mlp ? W1n : W1d;
  const int aoff = (mlp ? 5 : 0) + 64*half;
  const int zoff = 69 + 64*half;
  float acc[8];
  #pragma unroll
  for (int a = 0; a < 8; ++a) acc[a] = 0.f;
  #pragma unroll 2
  for (int f = 0; f < 64; f += 4) {
    const float w0 = W1[(aoff+f  )*128 + h];
    const float w1 = W1[(aoff+f+1)*128 + h];
    const float w2 = W1[(aoff+f+2)*128 + h];
    const float w3 = W1[(aoff+f+3)*128 + h];
    #pragma unroll
    for (int a = 0; a < 8; ++a) {
      const f32x4 xv = *(const f32x4*)&xs[a][f];
      acc[a] = fmaf(xv[3], w3, fmaf(xv[2], w2, fmaf(xv[1], w1, fmaf(xv[0], w0, acc[a]))));
    }
  }
  #pragma unroll 2
  for (int f = 64; f < 128; f += 4) {
    const float w0 = W1[(zoff+f  )*128 + h];
    const float w1 = W1[(zoff+f+1)*128 + h];
    const float w2 = W1[(zoff+f+2)*128 + h];
    const float w3 = W1[(zoff+f+3)*128 + h];
    #pragma unroll
    for (int a = 0; a < 8; ++a) {
      const f32x4 xv = *(const f32x4*)&xs[a][f];
      acc[a] = fmaf(xv[3], w3, fmaf(xv[2], w2, fmaf(xv[1], w1, fmaf(xv[0], w0, acc[a]))));
    }
  }
  const float bb = half ? 0.f : (mlp ? b1n[h] : b1d[h]);
  u16 pk[8];
  #pragma unroll
  for (int a = 0; a < 8; ++a) pk[a] = f2bf(acc[a] + bb);
  const int b = a0 >> 8;
  u16* dT = (u16*)((char*)ws16 + (mlp ? (half ? VT_N : UT_N) : (half ? VT_D : UT_D)));
  *(s16x8*)(dT + (b*128 + h)*256 + (a0 & 255)) = *(s16x8*)pk;
}

// =====================================================================
// kernel 2: main, barrier-free sigma-chained pipeline.
// Block: one mlp, 8 i's, 128 j's (4 steps x 4 waves x 8j). Wave owns 64 pairs.
// pass1: pre1[h,q] = [u'|v|0|Wg](A) x onehot/geom(B), K=32, relu->bf16 packed
//        IN-LANE into pass2 B-frags (sigma trick; no LDS round trip).
// pass2: h2[nn,q] = W2s(A, padded-stride LDS, imm-folded addrs) x h1(B, regs),
//        K=128, C-init = b2 (free bias).
// pass3: e[q] = sum relu(h2)*W3 in-lane + 2 shfl; direct global write.
__global__ __launch_bounds__(256, 2) void k_main(
    const float* __restrict__ af, const float* __restrict__ mask,
    const float* __restrict__ W1d, const float* __restrict__ b2d, const float* __restrict__ W3d, const float* __restrict__ b3d,
    const float* __restrict__ W1n, const float* __restrict__ b2n, const float* __restrict__ W3n, const float* __restrict__ b3n,
    const u16* __restrict__ ws16, float* __restrict__ e_raw, float* __restrict__ out) {
  const int t   = threadIdx.x;
  const int i0  = blockIdx.x * 8;
  const int mlp = blockIdx.y & 1, jc = blockIdx.y >> 1;
  const int b   = blockIdx.z;

  __shared__ u16 w2s[128*136];     // W2s rows padded to 136 (2-way banks, imm offsets)
  __shared__ float b2w3f[2][128];
  __shared__ float maskF[256];

  const u16* W2s_g = (const u16*)((const char*)ws16 + (mlp ? W2T_N : W2T_D));
  {
    const int row = t >> 1, c0 = (t & 1) * 64;
    #pragma unroll
    for (int w = 0; w < 8; ++w) {
      s16x8 v = *(const s16x8*)(W2s_g + row*128 + c0 + w*8);
      *(s16x8*)&w2s[row*136 + c0 + w*8] = v;
    }
  }
  if (t < 128) b2w3f[0][t] = (mlp ? b2n : b2d)[t];
  else         b2w3f[1][t-128] = (mlp ? W3n : W3d)[t-128];
  maskF[t] = mask[b*256 + t];
  const float b3v = (mlp ? b3n : b3d)[0];

  const int wv = t >> 6, l = t & 63, x = l & 15, g = l >> 4;
  const int xh = x >> 3, xl = x & 7;
  const int lanebase = 136*x + 8*g;   // per-lane w2s base (imm adds the rest)

  const u16* uT = (const u16*)((const char*)ws16 + (mlp ? UT_N : UT_D));
  const u16* vT = (const u16*)((const char*)ws16 + (mlp ? VT_N : VT_D));
  const float* W1 = mlp ? W1n : W1d;
  const int grow = mlp ? 0 : 128;

  // ---- persistent pass-1 A-frags: g0 = u'_i octet (block-static),
  //      g1 = v_j octet (per step), g2 = 0, g3 = Wg octet (static) ----
  s16x8 Af[8];
  #pragma unroll
  for (int m = 0; m < 8; ++m) {
    u32x4 a = {0u, 0u, 0u, 0u};
    if (g == 0) {
      a = *(const u32x4*)(uT + (b*128 + 16*m + x)*256 + i0);
    } else if (g == 3) {
      const int h = 16*m + x;
      const float w0 = W1[(grow+0)*128 + h], w1 = W1[(grow+1)*128 + h];
      const float w2 = W1[(grow+2)*128 + h], w3 = W1[(grow+3)*128 + h];
      const float w4 = W1[(grow+4)*128 + h];
      a[0] = cvt_pk_bf16(w0, w1); a[1] = cvt_pk_bf16(w2, w3);
      a[2] = cvt_pk_bf16(w4, 0.f); a[3] = 0u;
    }
    Af[m] = __builtin_bit_cast(s16x8, a);
  }

  // ---- static one-hot B-frags (g0: i-onehot, g1: j-onehot); g3 geom per step ----
  u32x4 B1u[4];
  #pragma unroll
  for (int n = 0; n < 4; ++n) {
    u32x4 v = {0u, 0u, 0u, 0u};
    if (g == 0) {
      const int il = 2*n + xh;
      v[il >> 1] = (il & 1) ? 0x3F800000u : 0x3F80u;
    } else if (g == 1) {
      v[xl >> 1] = (xl & 1) ? 0x3F800000u : 0x3F80u;
    }
    B1u[n] = v;
  }

  // ---- i-side geom components (block-static): comps 0,1,3,4 of i = i0+2n+xh ----
  f32x4 aic[4];
  #pragma unroll
  for (int n = 0; n < 4; ++n) {
    const float* ap = af + (b*256 + i0 + 2*n + xh)*64;
    aic[n][0] = ap[0]; aic[n][1] = ap[1]; aic[n][2] = ap[3]; aic[n][3] = ap[4];
  }

  int j0w = jc*128 + wv*8;
  // prefetch step-0 v-octets + j-side geom comps
  if (g == 1) {
    #pragma unroll
    for (int m = 0; m < 8; ++m)
      Af[m] = *(const s16x8*)(vT + (b*128 + 16*m + x)*256 + j0w);
  }
  float aj0, aj1, aj2, aj3;
  {
    const float* ap = af + (b*256 + j0w + xl)*64;
    aj0 = ap[0]; aj1 = ap[1]; aj2 = ap[3]; aj3 = ap[4];
  }

  __syncthreads();   // the only barrier: LDS staging complete

  const f32x4 zero4 = {0.f, 0.f, 0.f, 0.f};
  #pragma unroll 1
  for (int s = 0; s < 4; ++s, j0w += 32) {
    // ---- geom -> B1u g3 octet (k24..28 = rp0,rp1,rv0,rv1,dist) ----
    if (g == 3) {
      #pragma unroll
      for (int n = 0; n < 4; ++n) {
        const float rp0 = aj0 - aic[n][0], rp1 = aj1 - aic[n][1];
        const float rv0 = aj2 - aic[n][2], rv1 = aj3 - aic[n][3];
        const float dist = sqrtf(rp0*rp0 + rp1*rp1);
        u32x4 v;
        v[0] = cvt_pk_bf16(rp0, rp1); v[1] = cvt_pk_bf16(rv0, rv1);
        v[2] = cvt_pk_bf16(dist, 0.f); v[3] = 0u;
        B1u[n] = v;
      }
    }

    // ---- pass 1 + in-lane relu/pack into pass-2 B-frags (sigma chain) ----
    u32x4 Bh1[4][4];   // [kk][n]
    #pragma unroll
    for (int m = 0; m < 8; ++m) {
      #pragma unroll
      for (int n = 0; n < 4; ++n) {
        f32x4 a = __builtin_amdgcn_mfma_f32_16x16x32_bf16(Af[m], as_frag(B1u[n]), zero4, 0, 0, 0);
        const u32 p0 = cvt_pk_bf16(fmaxf(a[0], 0.f), fmaxf(a[1], 0.f));
        const u32 p1 = cvt_pk_bf16(fmaxf(a[2], 0.f), fmaxf(a[3], 0.f));
        if ((m & 1) == 0) { Bh1[m>>1][n][0] = p0; Bh1[m>>1][n][1] = p1; }
        else              { Bh1[m>>1][n][2] = p0; Bh1[m>>1][n][3] = p1; }
      }
    }

    // ---- prefetch next step's v-octets + geom comps (lands under pass2) ----
    if (s < 3) {
      if (g == 1) {
        #pragma unroll
        for (int m = 0; m < 8; ++m)
          Af[m] = *(const s16x8*)(vT + (b*128 + 16*m + x)*256 + j0w + 32);
      }
      const float* ap = af + (b*256 + j0w + 32 + xl)*64;
      aj0 = ap[0]; aj1 = ap[1]; aj2 = ap[3]; aj3 = ap[4];
    }

    // ---- pass 2 (b2 as C-init) + pass 3 (in-lane reduce) ----
    float ep0 = 0.f, ep1 = 0.f, ep2 = 0.f, ep3 = 0.f;
    __builtin_amdgcn_s_setprio(1);
    #pragma unroll
    for (int nq = 0; nq < 4; ++nq) {
      f32x4 acc2[2][4];
      #pragma unroll
      for (int mq = 0; mq < 2; ++mq) {
        const int w = 2*nq + mq;
        const f32x4 b2c = *(const f32x4*)&b2w3f[0][16*w + 4*g];
        const s16x8 a20 = *(const s16x8*)&w2s[lanebase + 2176*w];
        #pragma unroll
        for (int n = 0; n < 4; ++n)
          acc2[mq][n] = __builtin_amdgcn_mfma_f32_16x16x32_bf16(a20, as_frag(Bh1[0][n]), b2c, 0, 0, 0);
        #pragma unroll
        for (int kk = 1; kk < 4; ++kk) {
          const s16x8 a2 = *(const s16x8*)&w2s[lanebase + 2176*w + 32*kk];
          #pragma unroll
          for (int n = 0; n < 4; ++n)
            acc2[mq][n] = __builtin_amdgcn_mfma_f32_16x16x32_bf16(a2, as_frag(Bh1[kk][n]), acc2[mq][n], 0, 0, 0);
        }
      }
      #pragma unroll
      for (int mq = 0; mq < 2; ++mq) {
        const int w = 2*nq + mq;
        const f32x4 w3v = *(const f32x4*)&b2w3f[1][16*w + 4*g];
        #pragma unroll
        for (int r = 0; r < 4; ++r) {
          ep0 += fmaxf(acc2[mq][0][r], 0.f) * w3v[r];
          ep1 += fmaxf(acc2[mq][1][r], 0.f) * w3v[r];
          ep2 += fmaxf(acc2[mq][2][r], 0.f) * w3v[r];
          ep3 += fmaxf(acc2[mq][3][r], 0.f) * w3v[r];
        }
      }
    }
    __builtin_amdgcn_s_setprio(0);
    ep0 += __shfl_xor(ep0, 16); ep0 += __shfl_xor(ep0, 32);
    ep1 += __shfl_xor(ep1, 16); ep1 += __shfl_xor(ep1, 32);
    ep2 += __shfl_xor(ep2, 16); ep2 += __shfl_xor(ep2, 32);
    ep3 += __shfl_xor(ep3, 16); ep3 += __shfl_xor(ep3, 32);

    // lane writes pair q = 16g + x  ->  (iloc = 2g+xh, jloc = xl)
    const float es = (g == 0) ? ep0 : (g == 1) ? ep1 : (g == 2) ? ep2 : ep3;
    const int gi = i0 + 2*g + xh, gj = j0w + xl;
    const float e = es + b3v;
    const int off = (b << 16) + (gi << 8) + gj;
    if (mlp == 0) {
      const bool keep = (maskF[gi] * maskF[gj] > 0.5f) && (gi != gj);
      out[off] = keep ? e : 1000000.0f;
    } else {
      e_raw[off] = e;
    }
  }
}

// =====================================================================
// kernel 3: e_none symmetrize + mask (tile-pair, coalesced).
__global__ __launch_bounds__(256) void k_sym(
    const float* __restrict__ e_raw, const float* __restrict__ mask, float* __restrict__ out) {
  const int tp = blockIdx.x, b = blockIdx.y;
  int ti, tj;
  if (tp < 4)      { ti = 0; tj = tp; }
  else if (tp < 7) { ti = 1; tj = tp - 3; }
  else if (tp < 9) { ti = 2; tj = tp - 5; }
  else             { ti = 3; tj = 3; }
  __shared__ float E1[64][65], E2[64][65];
  __shared__ float mI[64], mJ[64];
  const int t = threadIdx.x;
  const int i0 = ti*64, j0 = tj*64, base = b << 16;
  for (int idx = t; idx < 4096; idx += 256) {
    const int r = idx >> 6, c = idx & 63;
    E1[r][c] = e_raw[base + (i0 + r)*256 + j0 + c];
    E2[r][c] = e_raw[base + (j0 + r)*256 + i0 + c];
  }
  if (t < 64)       mI[t] = mask[b*256 + i0 + t];
  else if (t < 128) mJ[t-64] = mask[b*256 + j0 + (t-64)];
  __syncthreads();
  for (int idx = t; idx < 4096; idx += 256) {
    const int r = idx >> 6, c = idx & 63;
    const int i = i0 + r, j = j0 + c;
    float v = 1000000.0f;
    if ((mI[r]*mJ[c] > 0.5f) && (i != j)) v = 0.5f*(E1[r][c] + E2[c][r]);
    out[524288 + base + i*256 + j] = v;
  }
  if (ti != tj) {
    for (int idx = t; idx < 4096; idx += 256) {
      const int r = idx >> 6, c = idx & 63;
      float v = 1000000.0f;
      if (mJ[r]*mI[c] > 0.5f) v = 0.5f*(E2[r][c] + E1[c][r]);
      out[524288 + base + (j0 + r)*256 + i0 + c] = v;
    }
  }
}

extern "C" void kernel_launch(void* const* d_in, const int* in_sizes, int n_in,
                              void* d_out, int out_size, void* d_ws, size_t ws_size,
                              hipStream_t stream) {
  const float* af   = (const float*)d_in[0];
  const float* zm   = (const float*)d_in[1];
  const float* zlv  = (const float*)d_in[2];
  const float* mask = (const float*)d_in[3];
  const float* W1d  = (const float*)d_in[4];
  const float* b1d  = (const float*)d_in[5];
  const float* W2d  = (const float*)d_in[6];
  const float* b2d  = (const float*)d_in[7];
  const float* W3d  = (const float*)d_in[8];
  const float* b3d  = (const float*)d_in[9];
  const float* W1n  = (const float*)d_in[10];
  const float* b1n  = (const float*)d_in[11];
  const float* W2n  = (const float*)d_in[12];
  const float* b2n  = (const float*)d_in[13];
  const float* W3n  = (const float*)d_in[14];
  const float* b3n  = (const float*)d_in[15];

  u16*   ws16  = (u16*)d_ws;
  float* e_raw = (float*)((char*)d_ws + ERAW);
  float* out   = (float*)d_out;

  k_uvw<<<dim3(257, 2), 256, 0, stream>>>(af, zm, zlv, W1d, b1d, W1n, b1n, W2d, W2n, ws16);
  k_main<<<dim3(32, 4, 8), 256, 0, stream>>>(af, mask, W1d, b2d, W3d, b3d,
                                             W1n, b2n, W3n, b3n, ws16, e_raw, out);
  k_sym<<<dim3(10, 8), 256, 0, stream>>>(e_raw, mask, out);
}